// Round 2
// baseline (5608.918 us; speedup 1.0000x reference)
//
#include <hip/hip_runtime.h>
#include <math.h>

#define NSTAGES 8
#define NCODES  1024
#define DIM     256
#define NROWS   131072
#define TM      64
#define EPSV    1e-12f

// padded ks-block stride (in shorts): 64 frags * 8 + 8 = 520 (1040 B, bank-rotates 4/ks)
#define KSTRIDE 520

typedef __attribute__((ext_vector_type(8))) short bf16x8;
typedef __attribute__((ext_vector_type(4))) float f32x4;

__device__ __forceinline__ unsigned fkey(float f) {
    unsigned u = __float_as_uint(f);
    return (u & 0x80000000u) ? ~u : (u | 0x80000000u);
}
__device__ __forceinline__ float bf2f(short h) {
    return __uint_as_float(((unsigned)(unsigned short)h) << 16);
}
// split v into RNE-high + truncated-low bf16 (same 2^-17-class error as double-RNE,
// but low path is sub+shr instead of a full RNE sequence)
__device__ __forceinline__ void split2(float v, short& h, short& l) {
    unsigned u  = __float_as_uint(v);
    unsigned hr = u + 0x7fffu + ((u >> 16) & 1u);
    h = (short)(hr >> 16);
    float hf = __uint_as_float(hr & 0xffff0000u);
    l = (short)(__float_as_uint(v - hf) >> 16);
}

// ---------------- prep: codebooks -> B-fragment-linear bf16 split + norms ----
// grid: 8 stages * 16 chunks of 64 codes; block 256
__global__ __launch_bounds__(256) void prep_kernel(const float* __restrict__ cb,
                                                   short* __restrict__ chF,
                                                   short* __restrict__ clF,
                                                   float* __restrict__ cn) {
    __shared__ float tile[64][260];
    __shared__ float pr[256];
    int s  = blockIdx.x >> 4;
    int c0 = (blockIdx.x & 15) * 64;
    int t  = threadIdx.x;
    const float4* src = (const float4*)(cb + ((size_t)s * NCODES + c0) * DIM);
#pragma unroll
    for (int i = 0; i < 16; ++i) {
        int e4 = t + 256 * i;
        int c  = e4 >> 6;
        int d4 = (e4 & 63) * 4;
        *(float4*)&tile[c][d4] = src[e4];
    }
    __syncthreads();
    {
        int c = t >> 2, q = t & 3;
        float sum = 0.f;
#pragma unroll 16
        for (int d = q * 64; d < q * 64 + 64; ++d) { float x = tile[c][d]; sum += x * x; }
        pr[t] = sum;
    }
    __syncthreads();
    if (t < 64) cn[(size_t)s * NCODES + c0 + t] = pr[4*t] + pr[4*t+1] + pr[4*t+2] + pr[4*t+3];
    // fragment writes: B[k][n] layout, lane = (k-quad)*16 + n_local, 8 bf16/lane
#pragma unroll
    for (int i = 0; i < 8; ++i) {
        int fi   = t + 256 * i;          // 2048 fragments: [nt_l:4][ks:8][lane:64]
        int nt_l = fi >> 9;
        int rem  = fi & 511;
        int ks   = rem >> 6;
        int lf   = rem & 63;
        int q    = lf >> 4;
        int nl   = lf & 15;
        int code = nt_l * 16 + nl;
        int kb   = ks * 32 + q * 8;
        bf16x8 hh, ll;
#pragma unroll
        for (int j = 0; j < 8; ++j) {
            short h, l;
            split2(tile[code][kb + j], h, l);
            hh[j] = h;
            ll[j] = l;
        }
        size_t off = ((((size_t)s * 64 + (c0 >> 4) + nt_l) * 8 + ks) * 64 + lf) * 8;
        *(bf16x8*)&chF[off] = hh;
        *(bf16x8*)&clF[off] = ll;
    }
}

// ---------------- init used tail of d_out ----------------
__global__ void init_used_kernel(const int* __restrict__ cbu, float* __restrict__ used) {
    int i = blockIdx.x * 256 + threadIdx.x;
    if (i < NSTAGES * NCODES) used[i] = (float)cbu[i];
}

// ---------------- main fused RVQ (MFMA) ----------------
// block 256 = 4 waves; 64 rows/block; wave w handles codes [w*256, w*256+256)
__global__ __launch_bounds__(256, 2) void rvq_kernel(const float* __restrict__ input,
                                                     const float* __restrict__ cb,
                                                     const short* __restrict__ chF,
                                                     const short* __restrict__ clF,
                                                     const float* __restrict__ cn,
                                                     const float* __restrict__ noise,
                                                     const int* __restrict__ cbu,
                                                     const int* __restrict__ tmp,
                                                     float* __restrict__ out,
                                                     float* __restrict__ used) {
    __shared__ __align__(16) short rhF[4 * 8 * KSTRIDE];   // 32.5 KB  A-frag rh
    __shared__ __align__(16) short rlF[4 * 8 * KSTRIDE];   // 32.5 KB  A-frag rl
    __shared__ unsigned long long bestkey[TM];
    __shared__ float pr[256], pn[256], scl[TM];

    int t    = threadIdx.x;
    int w    = t >> 6;
    int lane = t & 63;
    int row0 = blockIdx.x * TM;
    int row  = t >> 2;          // update/epilogue mapping: 4 threads per row
    int q4   = t & 3;
    const float* inp = input + (size_t)row0 * DIM;

    // ---- initial: input -> rh/rl A-fragments ----
    {
        const float4* ip4 = (const float4*)(inp + row * DIM + q4 * 64);
#pragma unroll
        for (int a = 0; a < 2; ++a) {
            int ks = q4 * 2 + a;
#pragma unroll
            for (int b = 0; b < 4; ++b) {
                float4 v0 = ip4[a * 8 + b * 2];
                float4 v1 = ip4[a * 8 + b * 2 + 1];
                float v[8] = {v0.x, v0.y, v0.z, v0.w, v1.x, v1.y, v1.z, v1.w};
                bf16x8 hh, ll;
#pragma unroll
                for (int j = 0; j < 8; ++j) {
                    short h, l;
                    split2(v[j], h, l);
                    hh[j] = h;
                    ll[j] = l;
                }
                int off = ((row >> 4) * 8 + ks) * KSTRIDE + (b * 16 + (row & 15)) * 8;
                *(bf16x8*)&rhF[off] = hh;
                *(bf16x8*)&rlF[off] = ll;
            }
        }
    }
    if (t < TM) bestkey[t] = ~0ULL;

    // ---- persistent B-fragment ring buffers ----
    // Bh: 4-deep ring, prefetch distance 2 (buf = iter & 3)
    // Bl: 2-deep ring, prefetch distance 1 (buf = iter & 1)
    bf16x8 Bh[4][4], Bl[2][4];
    {
        const short* chW0 = chF + (((size_t)w * 16) * 8 * 64 + lane) * 8;
        const short* clW0 = clF + (((size_t)w * 16) * 8 * 64 + lane) * 8;
#pragma unroll
        for (int nn = 0; nn < 4; ++nn) {
            Bh[0][nn] = *(const bf16x8*)&chW0[nn * 4096];
            Bh[1][nn] = *(const bf16x8*)&chW0[nn * 4096 + 512];
            Bl[0][nn] = *(const bf16x8*)&clW0[nn * 4096];
        }
    }

#pragma unroll 1
    for (int s = 0; s < NSTAGES; ++s) {
        __syncthreads();

        const short* chW = chF + ((((size_t)s * 64 + w * 16) * 8) * 64 + lane) * 8;
        const short* clW = clF + ((((size_t)s * 64 + w * 16) * 8) * 64 + lane) * 8;
        const float* cnL = cn + (size_t)s * NCODES + w * 256 + (lane & 15);

        float best[16];
        int   bcode[16];
#pragma unroll
        for (int i = 0; i < 16; ++i) { best[i] = INFINITY; bcode[i] = 0; }

#pragma unroll 1
        for (int cc = 0; cc < 4; ++cc) {
            const short* chC = chW + (size_t)cc * 16384;
            const short* clC = clW + (size_t)cc * 16384;
            // next-chunk base (next cc, or next stage's cc0 — issued before the
            // serial reduce/update phase so the loads stay in flight across it)
            const short* chN;
            const short* clN;
            bool pfok;
            if (cc < 3) { chN = chC + 16384; clN = clC + 16384; pfok = true; }
            else        { chN = chW + 262144; clN = clW + 262144; pfok = (s < 7); }

            float cnn[4];
#pragma unroll
            for (int nn = 0; nn < 4; ++nn) cnn[nn] = cnL[cc * 64 + nn * 16];

            f32x4 acc[4][4];
#pragma unroll
            for (int mt = 0; mt < 4; ++mt)
#pragma unroll
                for (int nn = 0; nn < 4; ++nn) acc[mt][nn] = (f32x4){0.f, 0.f, 0.f, 0.f};

#pragma unroll
            for (int ks = 0; ks < 8; ++ks) {
                // --- Bh prefetch: iter+2 ---
                if (ks <= 5) {
#pragma unroll
                    for (int nn = 0; nn < 4; ++nn)
                        Bh[(ks + 2) & 3][nn] = *(const bf16x8*)&chC[nn * 4096 + (ks + 2) * 512];
                } else if (pfok) {
#pragma unroll
                    for (int nn = 0; nn < 4; ++nn)
                        Bh[(ks + 2) & 3][nn] = *(const bf16x8*)&chN[nn * 4096 + (ks - 6) * 512];
                }
                // --- Bl prefetch: iter+1 ---
                if (ks <= 6) {
#pragma unroll
                    for (int nn = 0; nn < 4; ++nn)
                        Bl[(ks + 1) & 1][nn] = *(const bf16x8*)&clC[nn * 4096 + (ks + 1) * 512];
                } else if (pfok) {
#pragma unroll
                    for (int nn = 0; nn < 4; ++nn)
                        Bl[0][nn] = *(const bf16x8*)&clN[nn * 4096];
                }
                bf16x8 Ah[4], Al[4];
#pragma unroll
                for (int mt = 0; mt < 4; ++mt) {
                    int offA = (mt * 8 + ks) * KSTRIDE + lane * 8;
                    Ah[mt] = *(const bf16x8*)&rhF[offA];
                    Al[mt] = *(const bf16x8*)&rlF[offA];
                }
                __builtin_amdgcn_s_setprio(1);
#pragma unroll
                for (int mt = 0; mt < 4; ++mt)
#pragma unroll
                    for (int nn = 0; nn < 4; ++nn) {
                        acc[mt][nn] = __builtin_amdgcn_mfma_f32_16x16x32_bf16(Al[mt], Bh[ks & 3][nn], acc[mt][nn], 0, 0, 0);
                        acc[mt][nn] = __builtin_amdgcn_mfma_f32_16x16x32_bf16(Ah[mt], Bl[ks & 1][nn], acc[mt][nn], 0, 0, 0);
                        acc[mt][nn] = __builtin_amdgcn_mfma_f32_16x16x32_bf16(Ah[mt], Bh[ks & 3][nn], acc[mt][nn], 0, 0, 0);
                    }
                __builtin_amdgcn_s_setprio(0);
            }
            // fold scores: strict < keeps the earliest (= lowest) code on ties
            int code0 = w * 256 + cc * 64 + (lane & 15);
#pragma unroll
            for (int mt = 0; mt < 4; ++mt)
#pragma unroll
                for (int nn = 0; nn < 4; ++nn) {
                    int code = code0 + nn * 16;
                    float cno = cnn[nn];
#pragma unroll
                    for (int r = 0; r < 4; ++r) {
                        float sc = cno - 2.0f * acc[mt][nn][r];
                        int mi = mt * 4 + r;
                        if (sc < best[mi]) { best[mi] = sc; bcode[mi] = code; }
                    }
                }
        }
        // build sortable keys once per slot, then reduce across the 16 lanes
        unsigned long long mk[16];
#pragma unroll
        for (int i = 0; i < 16; ++i)
            mk[i] = ((unsigned long long)fkey(best[i]) << 32) | (unsigned)bcode[i];
#pragma unroll
        for (int d = 1; d < 16; d <<= 1)
#pragma unroll
            for (int i = 0; i < 16; ++i) {
                unsigned long long o = __shfl_xor(mk[i], d);
                if (o < mk[i]) mk[i] = o;
            }
        if ((lane & 15) == 0) {
#pragma unroll
            for (int mt = 0; mt < 4; ++mt)
#pragma unroll
                for (int r = 0; r < 4; ++r)
                    atomicMin(&bestkey[mt * 16 + (lane >> 4) * 4 + r], mk[mt * 4 + r]);
        }
        __syncthreads();

        // ---- residual update: res = (rh+rl) - cb[idx], re-split ----
        {
            int idx = (int)(bestkey[row] & 0xffffffffu);
            const float4* cp = (const float4*)(cb + ((size_t)s * NCODES + idx) * DIM + q4 * 64);
#pragma unroll
            for (int a = 0; a < 2; ++a) {
                int ks = q4 * 2 + a;
#pragma unroll
                for (int b = 0; b < 4; ++b) {
                    int off = ((row >> 4) * 8 + ks) * KSTRIDE + (b * 16 + (row & 15)) * 8;
                    bf16x8 hh = *(bf16x8*)&rhF[off];
                    bf16x8 ll = *(bf16x8*)&rlF[off];
                    float4 c0 = cp[a * 8 + b * 2];
                    float4 c1 = cp[a * 8 + b * 2 + 1];
                    float cv[8] = {c0.x, c0.y, c0.z, c0.w, c1.x, c1.y, c1.z, c1.w};
#pragma unroll
                    for (int j = 0; j < 8; ++j) {
                        float v = bf2f(hh[j]) + bf2f(ll[j]) - cv[j];
                        short h, l;
                        split2(v, h, l);
                        hh[j] = h;
                        ll[j] = l;
                    }
                    *(bf16x8*)&rhF[off] = hh;
                    *(bf16x8*)&rlF[off] = ll;
                }
            }
            if (t < TM) {
                int gi = (s << 10) + (int)(bestkey[t] & 0xffffffffu);
                used[gi] = (float)cbu[gi] + 1.0f;
            }
        }
        __syncthreads();
        if (t < TM) bestkey[t] = ~0ULL;
    }

    // ---- epilogue ----
    float sr = 0.f, sn = 0.f;
    {
        const float4* np4 = (const float4*)(noise + (size_t)(row0 + row) * DIM + q4 * 64);
#pragma unroll
        for (int a = 0; a < 2; ++a) {
            int ks = q4 * 2 + a;
#pragma unroll
            for (int b = 0; b < 4; ++b) {
                int off = ((row >> 4) * 8 + ks) * KSTRIDE + (b * 16 + (row & 15)) * 8;
                bf16x8 hh = *(bf16x8*)&rhF[off];
                bf16x8 ll = *(bf16x8*)&rlF[off];
#pragma unroll
                for (int j = 0; j < 8; ++j) {
                    float v = bf2f(hh[j]) + bf2f(ll[j]);
                    sr += v * v;
                }
            }
        }
#pragma unroll
        for (int i = 0; i < 16; ++i) {
            float4 nv = np4[i];
            sn += nv.x*nv.x + nv.y*nv.y + nv.z*nv.z + nv.w*nv.w;
        }
    }
    pr[t] = sr; pn[t] = sn;
    __syncthreads();
    if (t < TM) {
        float rs = pr[4*t] + pr[4*t+1] + pr[4*t+2] + pr[4*t+3];
        float ns = pn[4*t] + pn[4*t+1] + pn[4*t+2] + pn[4*t+3];
        scl[t] = sqrtf(rs) / sqrtf(ns) + EPSV;
    }
    __syncthreads();
    int tm = tmp[0];
    if (tm) {
        const float4* ib = (const float4*)inp;
        const float4* nb = (const float4*)(noise + (size_t)row0 * DIM);
        float4* ob = (float4*)(out + (size_t)row0 * DIM);
#pragma unroll
        for (int i = 0; i < 16; ++i) {
            int e4 = t + 256 * i;
            int r  = e4 >> 6;
            float sc = scl[r];
            float4 iv = ib[e4];
            float4 nv = nb[e4];
            float4 ov;
            ov.x = iv.x + sc * nv.x; ov.y = iv.y + sc * nv.y;
            ov.z = iv.z + sc * nv.z; ov.w = iv.w + sc * nv.w;
            ob[e4] = ov;
        }
    } else {
        float* op = out + (size_t)(row0 + row) * DIM + q4 * 64;
        const float* ipq = inp + row * DIM + q4 * 64;
#pragma unroll
        for (int a = 0; a < 2; ++a) {
            int ks = q4 * 2 + a;
#pragma unroll
            for (int b = 0; b < 4; ++b) {
                int off = ((row >> 4) * 8 + ks) * KSTRIDE + (b * 16 + (row & 15)) * 8;
                bf16x8 hh = *(bf16x8*)&rhF[off];
                bf16x8 ll = *(bf16x8*)&rlF[off];
#pragma unroll
                for (int j = 0; j < 8; ++j) {
                    int d = a * 32 + b * 8 + j;
                    op[d] = ipq[d] - (bf2f(hh[j]) + bf2f(ll[j]));
                }
            }
        }
    }
}

extern "C" void kernel_launch(void* const* d_in, const int* in_sizes, int n_in,
                              void* d_out, int out_size, void* d_ws, size_t ws_size,
                              hipStream_t stream) {
    const float* input = (const float*)d_in[0];
    const float* cb    = (const float*)d_in[1];
    const float* noise = (const float*)d_in[2];
    const int*   cbu   = (const int*)d_in[3];
    const int*   tm    = (const int*)d_in[4];
    float* out  = (float*)d_out;
    float* used = out + (size_t)NROWS * DIM;

    short* chF = (short*)d_ws;                               // 4 MB
    short* clF = chF + (size_t)NSTAGES * 64 * 8 * 64 * 8;    // 4 MB
    float* cn  = (float*)(clF + (size_t)NSTAGES * 64 * 8 * 64 * 8);  // 32 KB

    prep_kernel<<<NSTAGES * 16, 256, 0, stream>>>(cb, chF, clF, cn);
    init_used_kernel<<<(NSTAGES * NCODES + 255) / 256, 256, 0, stream>>>(cbu, used);
    rvq_kernel<<<NROWS / TM, 256, 0, stream>>>(input, cb, chF, clF, cn, noise, cbu, tm, out, used);
}

// Round 3
// 1525.437 us; speedup vs baseline: 3.6769x; 3.6769x over previous
//
#include <hip/hip_runtime.h>
#include <math.h>

#define NSTAGES 8
#define NCODES  1024
#define DIM     256
#define NROWS   131072
#define TM      64
#define EPSV    1e-12f

// padded ks-block stride (in shorts): 64 frags * 8 + 8 = 520 (1040 B, bank-rotates 4/ks)
#define KSTRIDE 520

typedef __attribute__((ext_vector_type(8))) short bf16x8;
typedef __attribute__((ext_vector_type(4))) float f32x4;

__device__ __forceinline__ unsigned fkey(float f) {
    unsigned u = __float_as_uint(f);
    return (u & 0x80000000u) ? ~u : (u | 0x80000000u);
}
__device__ __forceinline__ float bf2f(short h) {
    return __uint_as_float(((unsigned)(unsigned short)h) << 16);
}
// split v into RNE-high + truncated-low bf16 (same 2^-17-class error as double-RNE,
// but low path is sub+shr instead of a full RNE sequence)
__device__ __forceinline__ void split2(float v, short& h, short& l) {
    unsigned u  = __float_as_uint(v);
    unsigned hr = u + 0x7fffu + ((u >> 16) & 1u);
    h = (short)(hr >> 16);
    float hf = __uint_as_float(hr & 0xffff0000u);
    l = (short)(__float_as_uint(v - hf) >> 16);
}

// ---------------- prep: codebooks -> B-fragment-linear bf16 split + norms ----
// grid: 8 stages * 16 chunks of 64 codes; block 256
__global__ __launch_bounds__(256) void prep_kernel(const float* __restrict__ cb,
                                                   short* __restrict__ chF,
                                                   short* __restrict__ clF,
                                                   float* __restrict__ cn) {
    __shared__ float tile[64][260];
    __shared__ float pr[256];
    int s  = blockIdx.x >> 4;
    int c0 = (blockIdx.x & 15) * 64;
    int t  = threadIdx.x;
    const float4* src = (const float4*)(cb + ((size_t)s * NCODES + c0) * DIM);
#pragma unroll
    for (int i = 0; i < 16; ++i) {
        int e4 = t + 256 * i;
        int c  = e4 >> 6;
        int d4 = (e4 & 63) * 4;
        *(float4*)&tile[c][d4] = src[e4];
    }
    __syncthreads();
    {
        int c = t >> 2, q = t & 3;
        float sum = 0.f;
#pragma unroll 16
        for (int d = q * 64; d < q * 64 + 64; ++d) { float x = tile[c][d]; sum += x * x; }
        pr[t] = sum;
    }
    __syncthreads();
    if (t < 64) cn[(size_t)s * NCODES + c0 + t] = pr[4*t] + pr[4*t+1] + pr[4*t+2] + pr[4*t+3];
    // fragment writes: B[k][n] layout, lane = (k-quad)*16 + n_local, 8 bf16/lane
#pragma unroll
    for (int i = 0; i < 8; ++i) {
        int fi   = t + 256 * i;          // 2048 fragments: [nt_l:4][ks:8][lane:64]
        int nt_l = fi >> 9;
        int rem  = fi & 511;
        int ks   = rem >> 6;
        int lf   = rem & 63;
        int q    = lf >> 4;
        int nl   = lf & 15;
        int code = nt_l * 16 + nl;
        int kb   = ks * 32 + q * 8;
        bf16x8 hh, ll;
#pragma unroll
        for (int j = 0; j < 8; ++j) {
            short h, l;
            split2(tile[code][kb + j], h, l);
            hh[j] = h;
            ll[j] = l;
        }
        size_t off = ((((size_t)s * 64 + (c0 >> 4) + nt_l) * 8 + ks) * 64 + lf) * 8;
        *(bf16x8*)&chF[off] = hh;
        *(bf16x8*)&clF[off] = ll;
    }
}

// ---------------- init used tail of d_out ----------------
__global__ void init_used_kernel(const int* __restrict__ cbu, float* __restrict__ used) {
    int i = blockIdx.x * 256 + threadIdx.x;
    if (i < NSTAGES * NCODES) used[i] = (float)cbu[i];
}

// ---------------- main fused RVQ (MFMA) ----------------
// block 256 = 4 waves; 64 rows/block; wave w handles codes [w*256, w*256+256)
__global__ __launch_bounds__(256, 2) void rvq_kernel(const float* __restrict__ input,
                                                     const float* __restrict__ cb,
                                                     const short* __restrict__ chF,
                                                     const short* __restrict__ clF,
                                                     const float* __restrict__ cn,
                                                     const float* __restrict__ noise,
                                                     const int* __restrict__ cbu,
                                                     const int* __restrict__ tmp,
                                                     float* __restrict__ out,
                                                     float* __restrict__ used) {
    __shared__ __align__(16) short rhF[4 * 8 * KSTRIDE];   // 32.5 KB  A-frag rh
    __shared__ __align__(16) short rlF[4 * 8 * KSTRIDE];   // 32.5 KB  A-frag rl
    __shared__ unsigned long long bestkey[TM];
    __shared__ float pr[256], pn[256], scl[TM];

    int t    = threadIdx.x;
    int w    = t >> 6;
    int lane = t & 63;
    int row0 = blockIdx.x * TM;
    int row  = t >> 2;          // update/epilogue mapping: 4 threads per row
    int q4   = t & 3;
    const float* inp = input + (size_t)row0 * DIM;

    // ---- initial: input -> rh/rl A-fragments ----
    {
        const float4* ip4 = (const float4*)(inp + row * DIM + q4 * 64);
#pragma unroll
        for (int a = 0; a < 2; ++a) {
            int ks = q4 * 2 + a;
#pragma unroll
            for (int b = 0; b < 4; ++b) {
                float4 v0 = ip4[a * 8 + b * 2];
                float4 v1 = ip4[a * 8 + b * 2 + 1];
                float v[8] = {v0.x, v0.y, v0.z, v0.w, v1.x, v1.y, v1.z, v1.w};
                bf16x8 hh, ll;
#pragma unroll
                for (int j = 0; j < 8; ++j) {
                    short h, l;
                    split2(v[j], h, l);
                    hh[j] = h;
                    ll[j] = l;
                }
                int off = ((row >> 4) * 8 + ks) * KSTRIDE + (b * 16 + (row & 15)) * 8;
                *(bf16x8*)&rhF[off] = hh;
                *(bf16x8*)&rlF[off] = ll;
            }
        }
    }
    if (t < TM) bestkey[t] = ~0ULL;

#pragma unroll 1
    for (int s = 0; s < NSTAGES; ++s) {
        __syncthreads();

        const short* chW = chF + ((((size_t)s * 64 + w * 16) * 8) * 64 + lane) * 8;
        const short* clW = clF + ((((size_t)s * 64 + w * 16) * 8) * 64 + lane) * 8;
        const float* cnL = cn + (size_t)s * NCODES + w * 256 + (lane & 15);

        // running per-(row-slot) min as plain float + code register; 64-bit
        // sortable keys are built only once per slot at the end.
        float best[16];
        int   bcode[16];
#pragma unroll
        for (int i = 0; i < 16; ++i) { best[i] = INFINITY; bcode[i] = 0; }

#pragma unroll 1
        for (int cc = 0; cc < 4; ++cc) {
            const short* chC = chW + (size_t)cc * 16384;
            const short* clC = clW + (size_t)cc * 16384;
            float cnn[4];
#pragma unroll
            for (int nn = 0; nn < 4; ++nn) cnn[nn] = cnL[cc * 64 + nn * 16];

            f32x4 acc[4][4];
#pragma unroll
            for (int mt = 0; mt < 4; ++mt)
#pragma unroll
                for (int nn = 0; nn < 4; ++nn) acc[mt][nn] = (f32x4){0.f, 0.f, 0.f, 0.f};

            // 2-deep register double-buffer, prefetch distance 1 (R1-proven: no spill)
            bf16x8 Bh[2][4], Bl[2][4];
#pragma unroll
            for (int nn = 0; nn < 4; ++nn) {
                Bh[0][nn] = *(const bf16x8*)&chC[nn * 4096];
                Bl[0][nn] = *(const bf16x8*)&clC[nn * 4096];
            }
#pragma unroll 2
            for (int ks = 0; ks < 8; ++ks) {
                int cur = ks & 1;
                int nxt = cur ^ 1;
                if (ks < 7) {
#pragma unroll
                    for (int nn = 0; nn < 4; ++nn) {
                        Bh[nxt][nn] = *(const bf16x8*)&chC[nn * 4096 + (ks + 1) * 512];
                        Bl[nxt][nn] = *(const bf16x8*)&clC[nn * 4096 + (ks + 1) * 512];
                    }
                }
                bf16x8 Ah[4], Al[4];
#pragma unroll
                for (int mt = 0; mt < 4; ++mt) {
                    int offA = (mt * 8 + ks) * KSTRIDE + lane * 8;
                    Ah[mt] = *(const bf16x8*)&rhF[offA];
                    Al[mt] = *(const bf16x8*)&rlF[offA];
                }
                __builtin_amdgcn_s_setprio(1);
#pragma unroll
                for (int mt = 0; mt < 4; ++mt)
#pragma unroll
                    for (int nn = 0; nn < 4; ++nn) {
                        acc[mt][nn] = __builtin_amdgcn_mfma_f32_16x16x32_bf16(Al[mt], Bh[cur][nn], acc[mt][nn], 0, 0, 0);
                        acc[mt][nn] = __builtin_amdgcn_mfma_f32_16x16x32_bf16(Ah[mt], Bl[cur][nn], acc[mt][nn], 0, 0, 0);
                        acc[mt][nn] = __builtin_amdgcn_mfma_f32_16x16x32_bf16(Ah[mt], Bh[cur][nn], acc[mt][nn], 0, 0, 0);
                    }
                __builtin_amdgcn_s_setprio(0);
            }
            // fold scores: strict < keeps the earliest (= lowest) code on ties,
            // identical selection semantics to the 64-bit-key version.
            int code0 = w * 256 + cc * 64 + (lane & 15);
#pragma unroll
            for (int mt = 0; mt < 4; ++mt)
#pragma unroll
                for (int nn = 0; nn < 4; ++nn) {
                    int code = code0 + nn * 16;
                    float cno = cnn[nn];
#pragma unroll
                    for (int r = 0; r < 4; ++r) {
                        float sc = cno - 2.0f * acc[mt][nn][r];
                        int mi = mt * 4 + r;
                        if (sc < best[mi]) { best[mi] = sc; bcode[mi] = code; }
                    }
                }
        }
        // build sortable keys once per slot, then reduce across the 16 lanes
        unsigned long long mk[16];
#pragma unroll
        for (int i = 0; i < 16; ++i)
            mk[i] = ((unsigned long long)fkey(best[i]) << 32) | (unsigned)bcode[i];
#pragma unroll
        for (int d = 1; d < 16; d <<= 1)
#pragma unroll
            for (int i = 0; i < 16; ++i) {
                unsigned long long o = __shfl_xor(mk[i], d);
                if (o < mk[i]) mk[i] = o;
            }
        if ((lane & 15) == 0) {
#pragma unroll
            for (int mt = 0; mt < 4; ++mt)
#pragma unroll
                for (int r = 0; r < 4; ++r)
                    atomicMin(&bestkey[mt * 16 + (lane >> 4) * 4 + r], mk[mt * 4 + r]);
        }
        __syncthreads();

        // ---- residual update: res = (rh+rl) - cb[idx], re-split ----
        {
            int idx = (int)(bestkey[row] & 0xffffffffu);
            const float4* cp = (const float4*)(cb + ((size_t)s * NCODES + idx) * DIM + q4 * 64);
#pragma unroll
            for (int a = 0; a < 2; ++a) {
                int ks = q4 * 2 + a;
#pragma unroll
                for (int b = 0; b < 4; ++b) {
                    int off = ((row >> 4) * 8 + ks) * KSTRIDE + (b * 16 + (row & 15)) * 8;
                    bf16x8 hh = *(bf16x8*)&rhF[off];
                    bf16x8 ll = *(bf16x8*)&rlF[off];
                    float4 c0 = cp[a * 8 + b * 2];
                    float4 c1 = cp[a * 8 + b * 2 + 1];
                    float cv[8] = {c0.x, c0.y, c0.z, c0.w, c1.x, c1.y, c1.z, c1.w};
#pragma unroll
                    for (int j = 0; j < 8; ++j) {
                        float v = bf2f(hh[j]) + bf2f(ll[j]) - cv[j];
                        short h, l;
                        split2(v, h, l);
                        hh[j] = h;
                        ll[j] = l;
                    }
                    *(bf16x8*)&rhF[off] = hh;
                    *(bf16x8*)&rlF[off] = ll;
                }
            }
            if (t < TM) {
                int gi = (s << 10) + (int)(bestkey[t] & 0xffffffffu);
                used[gi] = (float)cbu[gi] + 1.0f;
            }
        }
        __syncthreads();
        if (t < TM) bestkey[t] = ~0ULL;
    }

    // ---- epilogue ----
    float sr = 0.f, sn = 0.f;
    {
        const float4* np4 = (const float4*)(noise + (size_t)(row0 + row) * DIM + q4 * 64);
#pragma unroll
        for (int a = 0; a < 2; ++a) {
            int ks = q4 * 2 + a;
#pragma unroll
            for (int b = 0; b < 4; ++b) {
                int off = ((row >> 4) * 8 + ks) * KSTRIDE + (b * 16 + (row & 15)) * 8;
                bf16x8 hh = *(bf16x8*)&rhF[off];
                bf16x8 ll = *(bf16x8*)&rlF[off];
#pragma unroll
                for (int j = 0; j < 8; ++j) {
                    float v = bf2f(hh[j]) + bf2f(ll[j]);
                    sr += v * v;
                }
            }
        }
#pragma unroll
        for (int i = 0; i < 16; ++i) {
            float4 nv = np4[i];
            sn += nv.x*nv.x + nv.y*nv.y + nv.z*nv.z + nv.w*nv.w;
        }
    }
    pr[t] = sr; pn[t] = sn;
    __syncthreads();
    if (t < TM) {
        float rs = pr[4*t] + pr[4*t+1] + pr[4*t+2] + pr[4*t+3];
        float ns = pn[4*t] + pn[4*t+1] + pn[4*t+2] + pn[4*t+3];
        scl[t] = sqrtf(rs) / sqrtf(ns) + EPSV;
    }
    __syncthreads();
    int tm = tmp[0];
    if (tm) {
        const float4* ib = (const float4*)inp;
        const float4* nb = (const float4*)(noise + (size_t)row0 * DIM);
        float4* ob = (float4*)(out + (size_t)row0 * DIM);
#pragma unroll
        for (int i = 0; i < 16; ++i) {
            int e4 = t + 256 * i;
            int r  = e4 >> 6;
            float sc = scl[r];
            float4 iv = ib[e4];
            float4 nv = nb[e4];
            float4 ov;
            ov.x = iv.x + sc * nv.x; ov.y = iv.y + sc * nv.y;
            ov.z = iv.z + sc * nv.z; ov.w = iv.w + sc * nv.w;
            ob[e4] = ov;
        }
    } else {
        float* op = out + (size_t)(row0 + row) * DIM + q4 * 64;
        const float* ipq = inp + row * DIM + q4 * 64;
#pragma unroll
        for (int a = 0; a < 2; ++a) {
            int ks = q4 * 2 + a;
#pragma unroll
            for (int b = 0; b < 4; ++b) {
                int off = ((row >> 4) * 8 + ks) * KSTRIDE + (b * 16 + (row & 15)) * 8;
                bf16x8 hh = *(bf16x8*)&rhF[off];
                bf16x8 ll = *(bf16x8*)&rlF[off];
#pragma unroll
                for (int j = 0; j < 8; ++j) {
                    int d = a * 32 + b * 8 + j;
                    op[d] = ipq[d] - (bf2f(hh[j]) + bf2f(ll[j]));
                }
            }
        }
    }
}

extern "C" void kernel_launch(void* const* d_in, const int* in_sizes, int n_in,
                              void* d_out, int out_size, void* d_ws, size_t ws_size,
                              hipStream_t stream) {
    const float* input = (const float*)d_in[0];
    const float* cb    = (const float*)d_in[1];
    const float* noise = (const float*)d_in[2];
    const int*   cbu   = (const int*)d_in[3];
    const int*   tm    = (const int*)d_in[4];
    float* out  = (float*)d_out;
    float* used = out + (size_t)NROWS * DIM;

    short* chF = (short*)d_ws;                               // 4 MB
    short* clF = chF + (size_t)NSTAGES * 64 * 8 * 64 * 8;    // 4 MB
    float* cn  = (float*)(clF + (size_t)NSTAGES * 64 * 8 * 64 * 8);  // 32 KB

    prep_kernel<<<NSTAGES * 16, 256, 0, stream>>>(cb, chF, clF, cn);
    init_used_kernel<<<(NSTAGES * NCODES + 255) / 256, 256, 0, stream>>>(cbu, used);
    rvq_kernel<<<NROWS / TM, 256, 0, stream>>>(input, cb, chF, clF, cn, noise, cbu, tm, out, used);
}